// Round 5
// baseline (188.708 us; speedup 1.0000x reference)
//
#include <hip/hip_runtime.h>

// AdaptiveDecayMemory: out = ((Q K^T * scale) ∘ W_decay) V Wo^T * out_scale
// B=4, T=2048, D=1024.  bf16 MFMA, fp32 accum.
// GEMM: 256x128 tile, 8 waves (4Mx2N, wave=64x64), BK=32,
// 3-buffer LDS rotation (72 KiB -> 2 blocks/CU), 1 barrier + vmcnt(3)/K-step.
// 2 blocks/CU gives cross-block MFMA<->LDS overlap (m114 mechanism).

using u16 = unsigned short;
typedef __bf16 bf16x8 __attribute__((ext_vector_type(8)));
typedef float f32x4 __attribute__((ext_vector_type(4)));

__device__ inline u16 f2bf(float f) {
  unsigned u = __builtin_bit_cast(unsigned, f);
  unsigned r = (u + 0x7FFFu + ((u >> 16) & 1u)) >> 16;   // RNE
  return (u16)r;
}

__device__ inline void gload16(const u16* g, u16* l) {
  __builtin_amdgcn_global_load_lds(
      (const __attribute__((address_space(1))) void*)g,
      (__attribute__((address_space(3))) void*)l, 16, 0, 0);
}

// ---------- fused x cast (fp32->bf16) + decay logit GEMV ----------
__global__ __launch_bounds__(256) void xcast_decay(const float* __restrict__ x,
    u16* __restrict__ Xbf, const float* __restrict__ Wd,
    const float* __restrict__ bd, float* __restrict__ ldec) {
  int row = blockIdx.x;
  int t = threadIdx.x;
  float4 f = reinterpret_cast<const float4*>(x + (size_t)row * 1024)[t];
  float4 g = reinterpret_cast<const float4*>(Wd)[t];
  ushort4 o;
  o.x = f2bf(f.x); o.y = f2bf(f.y); o.z = f2bf(f.z); o.w = f2bf(f.w);
  reinterpret_cast<ushort4*>(Xbf + (size_t)row * 1024)[t] = o;
  float s = f.x * g.x + f.y * g.y + f.z * g.z + f.w * g.w;
  #pragma unroll
  for (int off = 32; off > 0; off >>= 1) s += __shfl_xor(s, off);
  __shared__ float red[4];
  if ((t & 63) == 0) red[t >> 6] = s;
  __syncthreads();
  if (t == 0) {
    float tot = red[0] + red[1] + red[2] + red[3];
    float dec = 1.f / (1.f + expf(-(tot + bd[0])));
    ldec[row] = logf(dec + 1e-8f);
  }
}

// ---------- weight cast: [Wq;Wk;Wv;Wo] -> Wall ----------
__global__ __launch_bounds__(256) void wcast(const float* __restrict__ Wq,
    const float* __restrict__ Wk, const float* __restrict__ Wv,
    const float* __restrict__ Wo, u16* __restrict__ Wall) {
  int b = blockIdx.x;
  int m = b >> 10;
  const float* src = (m == 0) ? Wq : (m == 1) ? Wk : (m == 2) ? Wv : Wo;
  int i = ((b & 1023) * 256 + threadIdx.x) * 4;
  float4 f = *reinterpret_cast<const float4*>(src + i);
  ushort4 o;
  o.x = f2bf(f.x); o.y = f2bf(f.y); o.z = f2bf(f.z); o.w = f2bf(f.w);
  *reinterpret_cast<ushort4*>(Wall + (size_t)m * 1048576 + i) = o;
}

// ---------- 256x128 BK=32, 3-buffer, 2-blocks/CU GEMM ----------
// C[m,n] = sum_k A[m,k]*B[n,k]  (both K-contiguous).
// EPI 0: bf16 store.  EPI 1: decay epilogue -> bf16 (skip jt<2*it tiles).
// EPI 2: fp32 * scale_ptr[0].
// diag=1: K-loop starts at K-step it*8 (retrieval GEMM over upper-tri S).
// Per K-step per thread: 3 global_load_lds (2 A + 1 B) -> vmcnt(3).
// LDS chunk swizzle: slot (row r, 16B-chunk c) holds global chunk c ^ (r&3);
// staged via pre-swizzled per-lane global addr (linear LDS dest, rule #21).
template <int EPI>
__global__ __launch_bounds__(512, 4)
void gemm32(const u16* __restrict__ Ab, const u16* __restrict__ Bb,
            void* __restrict__ Cv, int lda, int ldb, int ldc, int K,
            int tiles_n, int diag, const float* __restrict__ ldec,
            const float* __restrict__ scale_ptr,
            long long abs_, long long bbs_, long long cbs_, int ld_stride) {
  __shared__ __align__(16) u16 lds2[36864];   // 3 x (A 256x32 | B 128x32) = 72 KiB

  const int batch = blockIdx.y;
  const u16* A = Ab + (size_t)batch * abs_;
  const u16* B = Bb + (size_t)batch * bbs_;

  const int it = blockIdx.x / tiles_n;
  const int jt = blockIdx.x % tiles_n;
  if (EPI == 1 && jt < 2 * it) return;   // all-zero anti-causal tiles, never read
  const int m0 = it * 256, n0 = jt * 128;

  const int tid = threadIdx.x;
  const int lane = tid & 63;
  const int w = tid >> 6;
  const int wm = w >> 1, wn = w & 1;     // wave = 64x64 of the 256x128 tile
  const int l15 = lane & 15, lhi = lane >> 4;   // frag row / k-chunk
  const int l4 = lane & 3, lr4 = lane >> 2;     // stage chunk / row-within-16
  const int gchunk = l4 ^ (lr4 & 3);            // pre-swizzled source chunk

  const int kt0 = diag ? it * 8 : 0;
  const int nkt = K / 32;
  const int span = nkt - kt0;            // >= 8 in all uses

  f32x4 acc[4][4];
  #pragma unroll
  for (int i = 0; i < 4; ++i)
    #pragma unroll
    for (int j = 0; j < 4; ++j) acc[i][j] = (f32x4)0.f;

  // per-thread staging source bases (advance by kt*32 each step)
  const u16* srcA0 = A + (size_t)(m0 +   0 + w * 16 + lr4) * lda + gchunk * 8;
  const u16* srcA1 = A + (size_t)(m0 + 128 + w * 16 + lr4) * lda + gchunk * 8;
  const u16* srcB  = B + (size_t)(n0 +       w * 16 + lr4) * ldb + gchunk * 8;

  auto stage = [&](int kt, int buf) {
    const int ko = kt * 32;
    u16* lb = &lds2[buf * 12288];
    gload16(srcA0 + ko, lb + (w * 16) * 32);
    gload16(srcA1 + ko, lb + (128 + w * 16) * 32);
    gload16(srcB  + ko, lb + 8192 + (w * 16) * 32);
  };

  // prologue: tiles 0,1 into bufs 0,1; drain tile 0 (3 = tile1 in flight)
  stage(kt0, 0);
  stage(kt0 + 1, 1);
  asm volatile("s_waitcnt vmcnt(3)" ::: "memory");
  __builtin_amdgcn_s_barrier();

  int bR = 0, bS = 2;
  for (int t = 0; t < span; ++t) {
    const u16* baseA = &lds2[bR * 12288];
    const u16* baseB = baseA + 8192;

    bf16x8 af[4], bv[4];
    #pragma unroll
    for (int mi = 0; mi < 4; ++mi) {
      int r = wm * 64 + mi * 16 + l15;
      int c = lhi ^ (r & 3);
      af[mi] = *reinterpret_cast<const bf16x8*>(&baseA[r * 32 + c * 8]);
    }
    #pragma unroll
    for (int ni = 0; ni < 4; ++ni) {
      int r = wn * 64 + ni * 16 + l15;
      int c = lhi ^ (r & 3);
      bv[ni] = *reinterpret_cast<const bf16x8*>(&baseB[r * 32 + c * 8]);
    }

    // prefetch K-step t+2 into the buffer last read at iter t-1 (barrier-fenced)
    int t2 = t + 2; if (t2 >= span) t2 = span - 1;   // tail: redundant refetch
    stage(kt0 + t2, bS);

    __builtin_amdgcn_s_setprio(1);
    #pragma unroll
    for (int mi = 0; mi < 4; ++mi)
      #pragma unroll
      for (int ni = 0; ni < 4; ++ni)
        acc[mi][ni] = __builtin_amdgcn_mfma_f32_16x16x32_bf16(
            af[mi], bv[ni], acc[mi][ni], 0, 0, 0);
    __builtin_amdgcn_s_setprio(0);

    // drain K-step t+1 (issued at iter t-1); t+2's 3 loads stay in flight
    asm volatile("s_waitcnt vmcnt(3)" ::: "memory");
    __builtin_amdgcn_s_barrier();

    bR = (bR == 2) ? 0 : bR + 1;
    bS = (bS == 2) ? 0 : bS + 1;
  }
  asm volatile("s_waitcnt vmcnt(0)" ::: "memory");  // drain before exit

  // epilogue: frag (mi,ni) -> row m0+wm*64+mi*16+lhi*4+q, col n0+wn*64+ni*16+l15
  if (EPI == 0) {
    u16* C = (u16*)Cv + (size_t)batch * cbs_;
    #pragma unroll
    for (int mi = 0; mi < 4; ++mi)
      #pragma unroll
      for (int q = 0; q < 4; ++q) {
        int row = m0 + wm * 64 + mi * 16 + lhi * 4 + q;
        u16* crow = C + (size_t)row * ldc + n0 + wn * 64 + l15;
        #pragma unroll
        for (int ni = 0; ni < 4; ++ni) crow[ni * 16] = f2bf(acc[mi][ni][q]);
      }
  } else if (EPI == 1) {
    u16* C = (u16*)Cv + (size_t)batch * cbs_;
    const float* ldp = ldec + (size_t)batch * ld_stride;
    float ldv[4];
    #pragma unroll
    for (int ni = 0; ni < 4; ++ni) ldv[ni] = ldp[n0 + wn * 64 + ni * 16 + l15];
    const float sc = 0.03125f;   // 1/sqrt(1024)
    #pragma unroll
    for (int mi = 0; mi < 4; ++mi)
      #pragma unroll
      for (int q = 0; q < 4; ++q) {
        int row = m0 + wm * 64 + mi * 16 + lhi * 4 + q;
        u16* crow = C + (size_t)row * ldc + n0 + wn * 64 + l15;
        #pragma unroll
        for (int ni = 0; ni < 4; ++ni) {
          int col = n0 + wn * 64 + ni * 16 + l15;
          int d = col - row;
          float wgt = (d > 0) ? expf(ldv[ni] * (float)(d - 1)) : 0.f;
          crow[ni * 16] = f2bf(acc[mi][ni][q] * sc * wgt);
        }
      }
  } else {
    float* C = (float*)Cv + (size_t)batch * cbs_;
    const float sc = scale_ptr[0];
    #pragma unroll
    for (int mi = 0; mi < 4; ++mi)
      #pragma unroll
      for (int q = 0; q < 4; ++q) {
        int row = m0 + wm * 64 + mi * 16 + lhi * 4 + q;
        float* crow = C + (size_t)row * ldc + n0 + wn * 64 + l15;
        #pragma unroll
        for (int ni = 0; ni < 4; ++ni) crow[ni * 16] = acc[mi][ni][q] * sc;
      }
  }
}

extern "C" void kernel_launch(void* const* d_in, const int* in_sizes, int n_in,
                              void* d_out, int out_size, void* d_ws, size_t ws_size,
                              hipStream_t stream) {
  const float* x   = (const float*)d_in[0];
  const float* Wq  = (const float*)d_in[1];
  const float* Wk  = (const float*)d_in[2];
  const float* Wv  = (const float*)d_in[3];
  const float* Wo  = (const float*)d_in[4];
  const float* Wd  = (const float*)d_in[5];
  const float* bd  = (const float*)d_in[6];
  const float* osc = (const float*)d_in[7];
  float* out = (float*)d_out;

  char* ws = (char*)d_ws;
  size_t off = 0;
  u16* Xbf  = (u16*)(ws + off); off += (size_t)8192 * 1024 * 2;
  u16* Wall = (u16*)(ws + off); off += (size_t)4096 * 1024 * 2;
  u16* VT   = (u16*)(ws + off); off += (size_t)1024 * 8192 * 2;
  u16* S    = (u16*)(ws + off); off += (size_t)4 * 2048 * 2048 * 2;
  float* ldec = (float*)(ws + off); off += (size_t)8192 * 4;
  u16* QK   = (u16*)(ws + off); off += (size_t)8192 * 2048 * 2;
  u16* R    = QK;  // alias: QK dead once S built

  u16* Wqk = Wall;
  u16* Wvb = Wall + 2 * 1048576;
  u16* Wob = Wall + 3 * 1048576;

  // 1) casts + decay
  xcast_decay<<<8192, 256, 0, stream>>>(x, Xbf, Wd, bd, ldec);
  wcast<<<4096, 256, 0, stream>>>(Wq, Wk, Wv, Wo, Wall);

  // 2) QK = Xbf @ Wqk^T  [8192 x 2048]   (512 blocks = 2/CU, one pass)
  gemm32<0><<<dim3(32 * 16, 1), 512, 0, stream>>>(
      Xbf, Wqk, QK, 1024, 1024, 2048, 1024, 16, 0, nullptr, nullptr, 0, 0, 0, 0);

  // 3) VT = Wvb @ Xbf^T  [1024 x 8192]   (256 blocks)
  gemm32<0><<<dim3(4 * 64, 1), 512, 0, stream>>>(
      Wvb, Xbf, VT, 1024, 1024, 8192, 1024, 64, 0, nullptr, nullptr, 0, 0, 0, 0);

  // 4) S_b = (Q_b K_b^T /32) ∘ weights -> bf16  (288 live blocks, co-resident)
  gemm32<1><<<dim3(8 * 16, 4), 512, 0, stream>>>(
      QK, QK + 1024, S, 2048, 2048, 2048, 1024, 16, 0, ldec, nullptr,
      4194304LL, 4194304LL, 4194304LL, 2048);

  // 5) R_b = S_b @ V_b  [2048 x 1024], K-loop from diagonal  (256 blocks)
  gemm32<0><<<dim3(8 * 8, 4), 512, 0, stream>>>(
      S, VT, R, 2048, 8192, 1024, 2048, 8, 1, nullptr, nullptr,
      4194304LL, 2048LL, 2097152LL, 0);

  // 6) out = R @ Wo^T * out_scale  [8192 x 1024] fp32  (256 blocks)
  gemm32<2><<<dim3(32 * 8, 1), 512, 0, stream>>>(
      R, Wob, out, 1024, 1024, 1024, 1024, 8, 0, nullptr, osc, 0, 0, 0, 0);
}

// Round 6
// 186.515 us; speedup vs baseline: 1.0118x; 1.0118x over previous
//
#include <hip/hip_runtime.h>

// AdaptiveDecayMemory: out = ((Q K^T * scale) ∘ W_decay) V Wo^T * out_scale
// B=4, T=2048, D=1024.  bf16 MFMA, fp32 accum.
// gemmW: 256x128, 8 waves (4Mx2N, wave 64x64), BK=64, 3x48KB bufs,
//        2 sub-phases/K-tile {8 ds_read + 3 gload | bar | 16 MFMA | bar},
//        vmcnt(6) once per K-tile.   For QK / VT / out.
// gemmN: 128x128, 8 waves (2Mx4N, wave 64x32), BK=64, 3x32KB bufs,
//        1 phase/K-tile {12 ds_read + 4 gload | bar | 16 MFMA | vmcnt(4) bar}.
//        MODE 1: R (diag-start, batch-parity it flip for load balance)
//        MODE 2: S (compact upper-triangular grid, decay epilogue).

using u16 = unsigned short;
typedef __bf16 bf16x8 __attribute__((ext_vector_type(8)));
typedef float f32x4 __attribute__((ext_vector_type(4)));

__device__ inline u16 f2bf(float f) {
  unsigned u = __builtin_bit_cast(unsigned, f);
  unsigned r = (u + 0x7FFFu + ((u >> 16) & 1u)) >> 16;   // RNE
  return (u16)r;
}

__device__ inline void gload16(const u16* g, u16* l) {
  __builtin_amdgcn_global_load_lds(
      (const __attribute__((address_space(1))) void*)g,
      (__attribute__((address_space(3))) void*)l, 16, 0, 0);
}

// ---------- fused x cast (fp32->bf16) + decay logit GEMV ----------
__global__ __launch_bounds__(256) void xcast_decay(const float* __restrict__ x,
    u16* __restrict__ Xbf, const float* __restrict__ Wd,
    const float* __restrict__ bd, float* __restrict__ ldec) {
  int row = blockIdx.x;
  int t = threadIdx.x;
  float4 f = reinterpret_cast<const float4*>(x + (size_t)row * 1024)[t];
  float4 g = reinterpret_cast<const float4*>(Wd)[t];
  ushort4 o;
  o.x = f2bf(f.x); o.y = f2bf(f.y); o.z = f2bf(f.z); o.w = f2bf(f.w);
  reinterpret_cast<ushort4*>(Xbf + (size_t)row * 1024)[t] = o;
  float s = f.x * g.x + f.y * g.y + f.z * g.z + f.w * g.w;
  #pragma unroll
  for (int off = 32; off > 0; off >>= 1) s += __shfl_xor(s, off);
  __shared__ float red[4];
  if ((t & 63) == 0) red[t >> 6] = s;
  __syncthreads();
  if (t == 0) {
    float tot = red[0] + red[1] + red[2] + red[3];
    float dec = 1.f / (1.f + expf(-(tot + bd[0])));
    ldec[row] = logf(dec + 1e-8f);
  }
}

// ---------- weight cast ----------
__global__ __launch_bounds__(256) void wcast(const float* __restrict__ Wq,
    const float* __restrict__ Wk, const float* __restrict__ Wv,
    const float* __restrict__ Wo, u16* __restrict__ Wall) {
  int b = blockIdx.x;
  int m = b >> 10;
  const float* src = (m == 0) ? Wq : (m == 1) ? Wk : (m == 2) ? Wv : Wo;
  int i = ((b & 1023) * 256 + threadIdx.x) * 4;
  float4 f = *reinterpret_cast<const float4*>(src + i);
  ushort4 o;
  o.x = f2bf(f.x); o.y = f2bf(f.y); o.z = f2bf(f.z); o.w = f2bf(f.w);
  *reinterpret_cast<ushort4*>(Wall + (size_t)m * 1048576 + i) = o;
}

// ---------- gemmW: 256x128, BK=64, phased ----------
template <int EPI>   // 0: bf16 store, 2: fp32 * scale
__global__ __launch_bounds__(512, 1)
void gemmW(const u16* __restrict__ Ab, const u16* __restrict__ Bb,
           void* __restrict__ Cv, int lda, int ldb, int ldc, int K,
           int tiles_n, const float* __restrict__ scale_ptr,
           long long abs_, long long bbs_, long long cbs_) {
  __shared__ __align__(16) u16 lds2[73728];   // 3 x (A 32KB | B 16KB)

  const int batch = blockIdx.y;
  const u16* A = Ab + (size_t)batch * abs_;
  const u16* B = Bb + (size_t)batch * bbs_;

  const int it = blockIdx.x / tiles_n;
  const int jt = blockIdx.x % tiles_n;
  const int m0 = it * 256, n0 = jt * 128;

  const int tid = threadIdx.x;
  const int lane = tid & 63;
  const int w = tid >> 6;
  const int wm = w >> 1, wn = w & 1;     // wave = 64x64
  const int l15 = lane & 15, lhi = lane >> 4;
  const int lr8 = lane >> 3;
  const int schunk = (lane & 7) ^ lr8;   // conflict-free r&7 chunk swizzle

  const int span = K / 64;

  f32x4 acc[4][4];
  #pragma unroll
  for (int i = 0; i < 4; ++i)
    #pragma unroll
    for (int j = 0; j < 4; ++j) acc[i][j] = (f32x4)0.f;

  auto stageH = [&](int kt, int buf, int h) {
    const size_t kb = (size_t)kt * 64 + schunk * 8;
    u16* lb = &lds2[buf * 24576];
    if (h == 0) {
      gload16(A + (size_t)(m0 +       w * 8 + lr8) * lda + kb, lb + (w * 8) * 64);
      gload16(A + (size_t)(m0 +  64 + w * 8 + lr8) * lda + kb, lb + (64 + w * 8) * 64);
      gload16(B + (size_t)(n0 +       w * 8 + lr8) * ldb + kb, lb + 16384 + (w * 8) * 64);
    } else {
      gload16(A + (size_t)(m0 + 128 + w * 8 + lr8) * lda + kb, lb + (128 + w * 8) * 64);
      gload16(A + (size_t)(m0 + 192 + w * 8 + lr8) * lda + kb, lb + (192 + w * 8) * 64);
      gload16(B + (size_t)(n0 +  64 + w * 8 + lr8) * ldb + kb, lb + 16384 + (64 + w * 8) * 64);
    }
  };

  // prologue: tiles 0,1 -> bufs 0,1; drain tile0 (tile1's 6 in flight)
  stageH(0, 0, 0); stageH(0, 0, 1);
  stageH(1, 1, 0); stageH(1, 1, 1);
  asm volatile("s_waitcnt vmcnt(6)" ::: "memory");
  __builtin_amdgcn_s_barrier();

  int bR = 0, bS = 2;
  for (int t = 0; t < span; ++t) {
    const u16* baseA = &lds2[bR * 24576];
    const u16* baseB = baseA + 16384;
    int t2 = t + 2; if (t2 >= span) t2 = span - 1;

    #pragma unroll
    for (int kk = 0; kk < 2; ++kk) {
      bf16x8 af[4], bv[4];
      #pragma unroll
      for (int mi = 0; mi < 4; ++mi) {
        int r = wm * 64 + mi * 16 + l15;
        int s = (kk * 4 + lhi) ^ (r & 7);
        af[mi] = *reinterpret_cast<const bf16x8*>(&baseA[r * 64 + s * 8]);
      }
      #pragma unroll
      for (int ni = 0; ni < 4; ++ni) {
        int r = wn * 64 + ni * 16 + l15;
        int s = (kk * 4 + lhi) ^ (r & 7);
        bv[ni] = *reinterpret_cast<const bf16x8*>(&baseB[r * 64 + s * 8]);
      }
      stageH(t2, bS, kk);          // 3 gloads per sub-phase
      __builtin_amdgcn_s_barrier();          // zone switch: reads done
      __builtin_amdgcn_s_setprio(1);
      #pragma unroll
      for (int mi = 0; mi < 4; ++mi)
        #pragma unroll
        for (int ni = 0; ni < 4; ++ni)
          acc[mi][ni] = __builtin_amdgcn_mfma_f32_16x16x32_bf16(
              af[mi], bv[ni], acc[mi][ni], 0, 0, 0);
      __builtin_amdgcn_s_setprio(0);
      if (kk == 1) asm volatile("s_waitcnt vmcnt(6)" ::: "memory");
      __builtin_amdgcn_s_barrier();          // zone switch: MFMA done
    }

    bR = (bR == 2) ? 0 : bR + 1;
    bS = (bS == 2) ? 0 : bS + 1;
  }
  asm volatile("s_waitcnt vmcnt(0)" ::: "memory");

  if (EPI == 0) {
    u16* C = (u16*)Cv + (size_t)batch * cbs_;
    #pragma unroll
    for (int mi = 0; mi < 4; ++mi)
      #pragma unroll
      for (int q = 0; q < 4; ++q) {
        int row = m0 + wm * 64 + mi * 16 + lhi * 4 + q;
        u16* crow = C + (size_t)row * ldc + n0 + wn * 64 + l15;
        #pragma unroll
        for (int ni = 0; ni < 4; ++ni) crow[ni * 16] = f2bf(acc[mi][ni][q]);
      }
  } else {
    float* C = (float*)Cv + (size_t)batch * cbs_;
    const float sc = scale_ptr[0];
    #pragma unroll
    for (int mi = 0; mi < 4; ++mi)
      #pragma unroll
      for (int q = 0; q < 4; ++q) {
        int row = m0 + wm * 64 + mi * 16 + lhi * 4 + q;
        float* crow = C + (size_t)row * ldc + n0 + wn * 64 + l15;
        #pragma unroll
        for (int ni = 0; ni < 4; ++ni) crow[ni * 16] = acc[mi][ni][q] * sc;
      }
  }
}

// ---------- gemmN: 128x128, BK=64, 8 waves (2Mx4N, wave 64x32) ----------
// MODE 1: R  (it from bx>>3 with batch-parity flip; kt0 = 2*it; K=2048)
// MODE 2: S  (compact tri grid: bx in [0,136) -> (it,jt), jt>=it; K=1024)
template <int MODE>
__global__ __launch_bounds__(512, 1)
void gemmN(const u16* __restrict__ Ab, const u16* __restrict__ Bb,
           void* __restrict__ Cv, int lda, int ldb, int ldc,
           const float* __restrict__ ldec,
           long long abs_, long long bbs_, long long cbs_) {
  __shared__ __align__(16) u16 lds2[49152];   // 3 x (A 16KB | B 16KB)

  const int batch = blockIdx.y;
  const u16* A = Ab + (size_t)batch * abs_;
  const u16* B = Bb + (size_t)batch * bbs_;

  int it, jt, kt0, span;
  if (MODE == 1) {
    int itr = blockIdx.x >> 3;
    it = (batch >= 2) ? (15 - itr) : itr;   // pair heavy+light across rounds
    jt = blockIdx.x & 7;
    kt0 = 2 * it;
    span = 32 - 2 * it;                     // K=2048
  } else {
    int L = blockIdx.x;                      // 0..135 upper-tri enumeration
    it = 0;
    while (L >= 16 - it) { L -= 16 - it; ++it; }
    jt = it + L;
    kt0 = 0;
    span = 16;                               // K=1024
  }
  const int m0 = it * 128, n0 = jt * 128;

  const int tid = threadIdx.x;
  const int lane = tid & 63;
  const int w = tid >> 6;
  const int wm = w >> 2, wn = w & 3;     // wave = 64x32
  const int l15 = lane & 15, lhi = lane >> 4;
  const int lr8 = lane >> 3;
  const int schunk = (lane & 7) ^ lr8;

  f32x4 acc[4][2];
  #pragma unroll
  for (int i = 0; i < 4; ++i)
    #pragma unroll
    for (int j = 0; j < 2; ++j) acc[i][j] = (f32x4)0.f;

  auto stage = [&](int kt, int buf) {
    const size_t kb = (size_t)kt * 64 + schunk * 8;
    u16* lb = &lds2[buf * 16384];
    gload16(A + (size_t)(m0 +      w * 8 + lr8) * lda + kb, lb + (w * 8) * 64);
    gload16(A + (size_t)(m0 + 64 + w * 8 + lr8) * lda + kb, lb + (64 + w * 8) * 64);
    gload16(B + (size_t)(n0 +      w * 8 + lr8) * ldb + kb, lb + 8192 + (w * 8) * 64);
    gload16(B + (size_t)(n0 + 64 + w * 8 + lr8) * ldb + kb, lb + 8192 + (64 + w * 8) * 64);
  };

  stage(kt0, 0);
  stage(kt0 + 1, 1);
  asm volatile("s_waitcnt vmcnt(4)" ::: "memory");
  __builtin_amdgcn_s_barrier();

  int bR = 0, bS = 2;
  for (int t = 0; t < span; ++t) {
    const u16* baseA = &lds2[bR * 16384];
    const u16* baseB = baseA + 8192;

    bf16x8 af[4][2], bv[2][2];
    #pragma unroll
    for (int mi = 0; mi < 4; ++mi) {
      int r = wm * 64 + mi * 16 + l15;
      #pragma unroll
      for (int kk = 0; kk < 2; ++kk) {
        int s = (kk * 4 + lhi) ^ (r & 7);
        af[mi][kk] = *reinterpret_cast<const bf16x8*>(&baseA[r * 64 + s * 8]);
      }
    }
    #pragma unroll
    for (int ni = 0; ni < 2; ++ni) {
      int r = wn * 32 + ni * 16 + l15;
      #pragma unroll
      for (int kk = 0; kk < 2; ++kk) {
        int s = (kk * 4 + lhi) ^ (r & 7);
        bv[ni][kk] = *reinterpret_cast<const bf16x8*>(&baseB[r * 64 + s * 8]);
      }
    }

    int t2 = t + 2; if (t2 >= span) t2 = span - 1;
    stage(kt0 + t2, bS);

    __builtin_amdgcn_s_barrier();          // reads done -> MFMA zone
    __builtin_amdgcn_s_setprio(1);
    #pragma unroll
    for (int kk = 0; kk < 2; ++kk)
      #pragma unroll
      for (int mi = 0; mi < 4; ++mi)
        #pragma unroll
        for (int ni = 0; ni < 2; ++ni)
          acc[mi][ni] = __builtin_amdgcn_mfma_f32_16x16x32_bf16(
              af[mi][kk], bv[ni][kk], acc[mi][ni], 0, 0, 0);
    __builtin_amdgcn_s_setprio(0);
    asm volatile("s_waitcnt vmcnt(4)" ::: "memory");
    __builtin_amdgcn_s_barrier();

    bR = (bR == 2) ? 0 : bR + 1;
    bS = (bS == 2) ? 0 : bS + 1;
  }
  asm volatile("s_waitcnt vmcnt(0)" ::: "memory");

  u16* C = (u16*)Cv + (size_t)batch * cbs_;
  if (MODE == 1) {
    #pragma unroll
    for (int mi = 0; mi < 4; ++mi)
      #pragma unroll
      for (int q = 0; q < 4; ++q) {
        int row = m0 + wm * 64 + mi * 16 + lhi * 4 + q;
        u16* crow = C + (size_t)row * ldc + n0 + wn * 32 + l15;
        #pragma unroll
        for (int ni = 0; ni < 2; ++ni) crow[ni * 16] = f2bf(acc[mi][ni][q]);
      }
  } else {
    const float* ldp = ldec + (size_t)batch * 2048;
    float ldv[2];
    #pragma unroll
    for (int ni = 0; ni < 2; ++ni) ldv[ni] = ldp[n0 + wn * 32 + ni * 16 + l15];
    const float sc = 0.03125f;   // 1/sqrt(1024)
    #pragma unroll
    for (int mi = 0; mi < 4; ++mi)
      #pragma unroll
      for (int q = 0; q < 4; ++q) {
        int row = m0 + wm * 64 + mi * 16 + lhi * 4 + q;
        u16* crow = C + (size_t)row * ldc + n0 + wn * 32 + l15;
        #pragma unroll
        for (int ni = 0; ni < 2; ++ni) {
          int col = n0 + wn * 32 + ni * 16 + l15;
          int d = col - row;
          float wgt = (d > 0) ? expf(ldv[ni] * (float)(d - 1)) : 0.f;
          crow[ni * 16] = f2bf(acc[mi][ni][q] * sc * wgt);
        }
      }
  }
}

extern "C" void kernel_launch(void* const* d_in, const int* in_sizes, int n_in,
                              void* d_out, int out_size, void* d_ws, size_t ws_size,
                              hipStream_t stream) {
  const float* x   = (const float*)d_in[0];
  const float* Wq  = (const float*)d_in[1];
  const float* Wk  = (const float*)d_in[2];
  const float* Wv  = (const float*)d_in[3];
  const float* Wo  = (const float*)d_in[4];
  const float* Wd  = (const float*)d_in[5];
  const float* bd  = (const float*)d_in[6];
  const float* osc = (const float*)d_in[7];
  float* out = (float*)d_out;

  char* ws = (char*)d_ws;
  size_t off = 0;
  u16* Xbf  = (u16*)(ws + off); off += (size_t)8192 * 1024 * 2;
  u16* Wall = (u16*)(ws + off); off += (size_t)4096 * 1024 * 2;
  u16* VT   = (u16*)(ws + off); off += (size_t)1024 * 8192 * 2;
  u16* S    = (u16*)(ws + off); off += (size_t)4 * 2048 * 2048 * 2;
  float* ldec = (float*)(ws + off); off += (size_t)8192 * 4;
  u16* QK   = (u16*)(ws + off); off += (size_t)8192 * 2048 * 2;
  u16* R    = QK;  // alias: QK dead once S built

  u16* Wqk = Wall;
  u16* Wvb = Wall + 2 * 1048576;
  u16* Wob = Wall + 3 * 1048576;

  // 1) casts + decay
  xcast_decay<<<8192, 256, 0, stream>>>(x, Xbf, Wd, bd, ldec);
  wcast<<<4096, 256, 0, stream>>>(Wq, Wk, Wv, Wo, Wall);

  // 2) QK = Xbf @ Wqk^T  [8192 x 2048]   (512 blocks, 2 rounds/CU)
  gemmW<0><<<dim3(512, 1), 512, 0, stream>>>(
      Xbf, Wqk, QK, 1024, 1024, 2048, 1024, 16, nullptr, 0, 0, 0);

  // 3) VT = Wvb @ Xbf^T  [1024 x 8192]   (256 blocks)
  gemmW<0><<<dim3(256, 1), 512, 0, stream>>>(
      Wvb, Xbf, VT, 1024, 1024, 8192, 1024, 64, nullptr, 0, 0, 0);

  // 4) S_b = (Q_b K_b^T /32) ∘ weights -> bf16, compact tri grid (544 blocks)
  gemmN<2><<<dim3(136, 4), 512, 0, stream>>>(
      QK, QK + 1024, S, 2048, 2048, 2048, ldec,
      4194304LL, 4194304LL, 4194304LL);

  // 5) R_b = S_b @ V_b  [2048 x 1024], diag-start, balanced rounds (512 blocks)
  gemmN<1><<<dim3(128, 4), 512, 0, stream>>>(
      S, VT, R, 2048, 8192, 1024, nullptr,
      4194304LL, 2048LL, 2097152LL);

  // 6) out = R @ Wo^T * out_scale  [8192 x 1024] fp32  (256 blocks)
  gemmW<2><<<dim3(256, 1), 512, 0, stream>>>(
      R, Wob, out, 1024, 1024, 1024, 1024, 8, osc, 0, 0, 0);
}